// Round 6
// baseline (337.520 us; speedup 1.0000x reference)
//
#include <hip/hip_runtime.h>
#include <hip/hip_bf16.h>
#include <math.h>

// Problem constants (T=64, B=256, N=512)
#define TT 64
#define BB 256
#define NN 512

typedef int i32x4  __attribute__((ext_vector_type(4)));
typedef int i32x16 __attribute__((ext_vector_type(16)));

// global -> LDS direct DMA, 16B per lane. LDS dest must be wave-uniform base
// (HW adds lane*16); global src is per-lane.
__device__ __forceinline__ void gload16(const void* g, void* l) {
  __builtin_amdgcn_global_load_lds(
      (const __attribute__((address_space(1))) unsigned int*)g,
      (__attribute__((address_space(3))) unsigned int*)l, 16, 0, 0);
}

// ---------------------------------------------------------------------------
// K0: W -> 4 signed-i8 digit planes of round(W * 2^30). Exact reconstruction:
// W_int = d0 + (d1<<8) + (d2<<16) + (d3<<24); |W|<=0.0766 -> fits 27 bits.
// ---------------------------------------------------------------------------
__global__ __launch_bounds__(256) void wprep_kernel(
    const float* __restrict__ W, signed char* __restrict__ wd) {
  int i = blockIdx.x * 256 + threadIdx.x;
  float v = W[i];
  int q = __float2int_rn(v * 1073741824.0f);
  int d0 = ((q + 128) & 255) - 128; q = (q - d0) >> 8;
  int d1 = ((q + 128) & 255) - 128; q = (q - d1) >> 8;
  int d2 = ((q + 128) & 255) - 128; q = (q - d2) >> 8;
  wd[i]          = (signed char)d0;
  wd[262144 + i] = (signed char)d1;
  wd[524288 + i] = (signed char)d2;
  wd[786432 + i] = (signed char)q;   // |q| <= 9
}

// ---------------------------------------------------------------------------
// K1: fused front-end. One block per b. Stage x[:,b,:] (128KB) into LDS once,
// row-means -> spatial LIF (register/shfl chain), col-means -> temporal gate,
// main gated LIF scan -> u8 spikes. x read from HBM exactly once.
// ---------------------------------------------------------------------------
__global__ __launch_bounds__(512) void frontend_kernel(
    const float* __restrict__ x, unsigned char* __restrict__ spk) {
  extern __shared__ float xs[];          // [64][512] = 128 KB
  __shared__ float rms[TT];
  __shared__ float sp[TT];
  int b = blockIdx.x, tid = threadIdx.x;
  int l = tid & 63, w = tid >> 6;        // 8 waves
  #pragma unroll
  for (int p = 0; p < 16; ++p) {
    int f = p * 512 + tid;
    int t = f >> 7, c4 = f & 127;        // row t, float4 col c4
    gload16(x + (size_t)t * (BB * NN) + (size_t)b * NN + c4 * 4,
            (char*)xs + p * 8192 + w * 1024);
  }
  __syncthreads();                       // drains vmcnt(0) before barrier
  #pragma unroll
  for (int j = 0; j < 8; ++j) {          // wave w owns rows w*8..w*8+7
    int t = w * 8 + j;
    float s = 0.f;
    #pragma unroll
    for (int q = 0; q < 8; ++q) s += xs[t * 512 + q * 64 + l];
    #pragma unroll
    for (int off = 32; off; off >>= 1) s += __shfl_xor(s, off);
    if (l == 0) rms[t] = s;
  }
  float cs = 0.f;
  for (int t = 0; t < TT; ++t) cs += xs[t * 512 + tid];
  __syncthreads();
  // spatial LIF scan: wave 0, register chain via shfl broadcast
  if (w == 0) {
    float myrm = rms[l];
    float v = 0.f;
    unsigned long long mask = 0ull;
    #pragma unroll
    for (int t = 0; t < TT; ++t) {
      float m = __shfl(myrm, t) * (1.0f / 512.0f);
      v = v * 0.5f + m;                  // == v - v/2 + m exactly
      if (v >= 1.0f) { mask |= (1ull << t); v = 0.f; }
    }
    sp[l] = (float)((mask >> l) & 1ull);
  }
  __syncthreads();
  float te = (cs * (1.0f / 64.0f) >= 1.0f) ? 1.0f : 0.0f;
  float v = 0.f;
  unsigned char* sb = spk + (size_t)b * NN + tid;
  for (int t = 0; t < TT; ++t) {
    float xv = xs[t * 512 + tid];
    float a = xv + (xv * sp[t]) * (xv * te);  // ==xv exactly when a gate is 0
    v = v * 0.5f + a;
    unsigned char s = (v >= 1.0f) ? 1 : 0;
    sb[(size_t)t * (BB * NN)] = s;
    if (s) v = 0.f;
  }
}

// ---------------------------------------------------------------------------
// K2: i8 MFMA GEMM, 2x24KB double-buffer (48KB -> 3 blocks/CU, 12 waves/CU).
// Block: 4 waves (2x2) -> 128 rows x 64 cols; BK=64.
// Per iter t: lgkmcnt(0) [my prev-buf reads done]; vmcnt(0) [my stage of
// buf[t%2] landed]; s_barrier [publish]; issue STAGE(t+1) -> buf[(t+1)%2]
// (the buffer everyone just finished reading); ds_read buf[t%2]; 16 MFMA.
// Occupancy (12 waves/CU) provides the latency cover (m97 regime), not
// per-wave pipeline depth (R5 showed depth adds ~nothing at 8 waves/CU).
// ---------------------------------------------------------------------------
__global__ __launch_bounds__(256, 3) void gemm_kernel(
    const unsigned char* __restrict__ A, const signed char* __restrict__ Wd,
    float* __restrict__ C, float* __restrict__ pS, float* __restrict__ pQ) {
  __shared__ unsigned char sm[2][24576];
  int tid = threadIdx.x;
  int l = tid & 63, w = tid >> 6;
  int wr = w >> 1, wc = w & 1;
  int bx = blockIdx.x, by = blockIdx.y;
  int row0 = bx * 128, col0 = by * 64;
  int lr = l & 31, lh = l >> 5;

  i32x16 acc[2][4];
  #pragma unroll
  for (int f = 0; f < 2; ++f)
    #pragma unroll
    for (int d = 0; d < 4; ++d)
      #pragma unroll
      for (int j = 0; j < 16; ++j) acc[f][d][j] = 0;

  auto STAGE = [&](unsigned char* lbase, int kk) {
    #pragma unroll
    for (int j = 0; j < 2; ++j) {        // A chunks: c = wr_*4 + ff*2 + ss
      int c = j * 4 + w;
      int wr_ = c >> 2, ff = (c >> 1) & 1, ss = c & 1;
      gload16(A + (size_t)(row0 + wr_ * 64 + ff * 32 + lr) * NN + kk + ss * 32 + lh * 16,
              lbase + j * 4096 + w * 1024);
    }
    #pragma unroll
    for (int j = 0; j < 4; ++j) {        // B chunks: c = wc_*8 + dd*2 + ss
      int c = j * 4 + w;
      int wc_ = c >> 3, dd = (c >> 1) & 3, ss = c & 1;
      gload16(Wd + (size_t)dd * (NN * NN) + (size_t)(col0 + wc_ * 32 + lr) * NN + kk + ss * 32 + lh * 16,
              lbase + 8192 + j * 4096 + w * 1024);
    }
  };

  STAGE(sm[0], 0);
  #pragma unroll
  for (int t = 0; t < 8; ++t) {
    asm volatile("s_waitcnt lgkmcnt(0)" ::: "memory");  // my reads of prev buf done
    asm volatile("s_waitcnt vmcnt(0)" ::: "memory");    // my stage of buf[t%2] landed
    asm volatile("s_barrier" ::: "memory");             // all waves agree
    if (t < 7) STAGE(sm[(t + 1) & 1], (t + 1) * 64);    // refill freed buffer
    const unsigned char* bp = sm[t & 1];
    i32x4 a[2][2], bfr[4][2];
    #pragma unroll
    for (int f = 0; f < 2; ++f)
      #pragma unroll
      for (int s = 0; s < 2; ++s)
        a[f][s] = *(const i32x4*)(bp + ((wr * 2 + f) * 2 + s) * 1024 + l * 16);
    #pragma unroll
    for (int d = 0; d < 4; ++d)
      #pragma unroll
      for (int s = 0; s < 2; ++s)
        bfr[d][s] = *(const i32x4*)(bp + 8192 + ((wc * 4 + d) * 2 + s) * 1024 + l * 16);
    __builtin_amdgcn_s_setprio(1);
    #pragma unroll
    for (int s = 0; s < 2; ++s)
      #pragma unroll
      for (int f = 0; f < 2; ++f)
        #pragma unroll
        for (int d = 0; d < 4; ++d)
          acc[f][d] = __builtin_amdgcn_mfma_i32_32x32x32_i8(a[f][s], bfr[d][s], acc[f][d], 0, 0, 0);
    __builtin_amdgcn_s_setprio(0);
  }

  // epilogue: exact digit combine, C write, BN partials.
  // lanes lh=0/1 share a column, different rows -> combine across lane^32.
  int col = col0 + wc * 32 + lr;
  float sy = 0.f, sq = 0.f;
  #pragma unroll
  for (int f = 0; f < 2; ++f) {
    #pragma unroll
    for (int j = 0; j < 16; ++j) {
      int t2 = acc[f][2][j] + (acc[f][3][j] << 8);
      int t1 = acc[f][1][j] + (t2 << 8);
      long long tt = ((long long)t1 << 8) + (long long)acc[f][0][j];
      float y = (float)tt * 0x1p-30f;
      int row = row0 + wr * 64 + f * 32 + (j & 3) + 8 * (j >> 2) + 4 * lh;
      C[(size_t)row * NN + col] = y;
      sy += y; sq += y * y;
    }
  }
  sy += __shfl_xor(sy, 32);
  sq += __shfl_xor(sq, 32);
  if (lh == 0) {
    pS[(size_t)col * 256 + bx * 2 + wr] = sy;
    pQ[(size_t)col * 256 + bx * 2 + wr] = sq;
  }
}

// ---------------------------------------------------------------------------
// K3: reduce 256 BN partials per channel -> mu, inv-std
// ---------------------------------------------------------------------------
__global__ __launch_bounds__(512) void bnstatsB_kernel(
    const float* __restrict__ pS, const float* __restrict__ pQ,
    float* __restrict__ mu, float* __restrict__ inv) {
  int tid = threadIdx.x;
  int ch = blockIdx.x * 64 + (tid >> 3), p = tid & 7;
  const float* ps = pS + (size_t)ch * 256 + p * 32;
  const float* pq = pQ + (size_t)ch * 256 + p * 32;
  float s = 0.f, q = 0.f;
  #pragma unroll
  for (int i = 0; i < 32; ++i) { s += ps[i]; q += pq[i]; }
  #pragma unroll
  for (int off = 1; off < 8; off <<= 1) { s += __shfl_xor(s, off); q += __shfl_xor(q, off); }
  if (p == 0) {
    float mean = s * (1.0f / 16384.0f);
    float var  = q * (1.0f / 16384.0f) - mean * mean;
    mu[ch] = mean;
    inv[ch] = 1.0f / sqrtf(var + 1e-5f);
  }
}

// ---------------------------------------------------------------------------
// K4: BN normalize + final LIF scan, in-place on d_out, 16-deep load prefetch
// ---------------------------------------------------------------------------
__global__ __launch_bounds__(256) void final_kernel(
    float* __restrict__ y, const float* __restrict__ mu, const float* __restrict__ inv,
    const float* __restrict__ gamma, const float* __restrict__ beta) {
  int g = blockIdx.x * 256 + threadIdx.x;   // (b, m)
  int b = g >> 9, m = g & 511;
  float MU = mu[m], IV = inv[m], G = gamma[m], BE = beta[m];
  float* p = y + (size_t)b * NN + m;
  const size_t st = (size_t)BB * NN;
  float buf[16], nxt[16];
  #pragma unroll
  for (int j = 0; j < 16; ++j) buf[j] = p[(size_t)j * st];
  float v = 0.f;
  #pragma unroll
  for (int t0 = 0; t0 < 64; t0 += 16) {
    if (t0 + 16 < 64) {
      #pragma unroll
      for (int j = 0; j < 16; ++j) nxt[j] = p[(size_t)(t0 + 16 + j) * st];
    }
    #pragma unroll
    for (int j = 0; j < 16; ++j) {
      float xb = (buf[j] - MU) * IV * G + BE;
      v = v * 0.5f + xb;
      float s = (v >= 1.0f) ? 1.0f : 0.0f;
      p[(size_t)(t0 + j) * st] = s;
      if (s != 0.f) v = 0.f;
    }
    #pragma unroll
    for (int j = 0; j < 16; ++j) buf[j] = nxt[j];
  }
}

// ---------------------------------------------------------------------------
extern "C" void kernel_launch(void* const* d_in, const int* in_sizes, int n_in,
                              void* d_out, int out_size, void* d_ws, size_t ws_size,
                              hipStream_t stream) {
  const float* x     = (const float*)d_in[0];   // [T,B,N]
  const float* W     = (const float*)d_in[1];   // [N,N]
  const float* gamma = (const float*)d_in[2];   // [N]
  const float* beta  = (const float*)d_in[3];   // [N]
  float* out = (float*)d_out;                   // [T,B,N] fp32

  // workspace layout (~10.5 MB)
  char* ws = (char*)d_ws;
  signed char* wd       = (signed char*)ws;                 // 1,048,576
  unsigned char* spikes = (unsigned char*)(ws + 1048576);   // 8,388,608
  float* pS    = (float*)(ws + 9437184);                    //   524,288
  float* pQ    = (float*)(ws + 9961472);                    //   524,288
  float* bn_mu = (float*)(ws + 10485760);                   //     2,048
  float* bn_inv= (float*)(ws + 10487808);                   //     2,048

  wprep_kernel<<<dim3(1024), dim3(256), 0, stream>>>(W, wd);
  frontend_kernel<<<dim3(BB), dim3(512), 131072, stream>>>(x, spikes);
  gemm_kernel<<<dim3(128, 8), dim3(256), 0, stream>>>(spikes, wd, out, pS, pQ);
  bnstatsB_kernel<<<dim3(8), dim3(512), 0, stream>>>(pS, pQ, bn_mu, bn_inv);
  final_kernel<<<dim3(512), dim3(256), 0, stream>>>(out, bn_mu, bn_inv, gamma, beta);
}

// Round 7
// 143.255 us; speedup vs baseline: 2.3561x; 2.3561x over previous
//
#include <hip/hip_runtime.h>
#include <hip/hip_bf16.h>
#include <math.h>

// Problem constants (T=64, B=256, N=512)
#define TT 64
#define BB 256
#define NN 512

typedef int i32x4  __attribute__((ext_vector_type(4)));
typedef int i32x16 __attribute__((ext_vector_type(16)));

// global -> LDS direct DMA, 16B per lane. LDS dest is wave-uniform base
// (HW adds lane*16); global src is per-lane.
__device__ __forceinline__ void gload16(const void* g, void* l) {
  __builtin_amdgcn_global_load_lds(
      (const __attribute__((address_space(1))) unsigned int*)g,
      (__attribute__((address_space(3))) unsigned int*)l, 16, 0, 0);
}

// ---------------------------------------------------------------------------
// Chunk layout (shared by wprep / frontend / gemm):
// a 1KB chunk = one MFMA-ready 32rows x 32k i8 tile: byte(lane l, j) =
// M[group*32 + (l&31)][kchunk*32 + (l>>5)*16 + j].  gload16 from a chunk is
// lane-contiguous (base + l*16) -> perfectly coalesced, 16 lines/instr.
// ---------------------------------------------------------------------------

// K0: W -> 4 signed-i8 digit planes of round(W*2^30) in chunk layout.
// wdT[((cg*4 + d)*16 + kc)*1024 + l*16 + j]. Exact: W_int = d0+(d1<<8)+
// (d2<<16)+(d3<<24); |W|<=0.0766 -> 27 bits.
__global__ __launch_bounds__(256) void wprep_kernel(
    const float* __restrict__ W, signed char* __restrict__ wdT) {
  int i = blockIdx.x * 256 + threadIdx.x;   // i = m*512 + k
  int m = i >> 9, k = i & 511;
  float v = W[i];
  int q = __float2int_rn(v * 1073741824.0f);
  int d0 = ((q + 128) & 255) - 128; q = (q - d0) >> 8;
  int d1 = ((q + 128) & 255) - 128; q = (q - d1) >> 8;
  int d2 = ((q + 128) & 255) - 128; q = (q - d2) >> 8;
  int cg = m >> 5, kc = k >> 5, kh = (k >> 4) & 1, j = k & 15;
  int l = (m & 31) + 32 * kh;
  size_t base = ((size_t)(cg * 4) * 16 + kc) * 1024 + l * 16 + j;
  wdT[base        ] = (signed char)d0;      // digit d at base + d*16384
  wdT[base + 16384] = (signed char)d1;
  wdT[base + 32768] = (signed char)d2;
  wdT[base + 49152] = (signed char)q;       // |q| <= 9
}

// ---------------------------------------------------------------------------
// K1: fused front-end. One block per b. Stage x[:,b,:] (128KB) into LDS once,
// row-means -> spatial LIF (reg/shfl chain), col-means -> temporal gate,
// main gated LIF scan (column held in 64 regs) -> spikes written DIRECTLY in
// chunk layout (row r = t*256+b -> rg = t*8 + b>>5, l&31 = b&31).
// ---------------------------------------------------------------------------
__global__ __launch_bounds__(512) void frontend_kernel(
    const float* __restrict__ x, unsigned char* __restrict__ spkT) {
  extern __shared__ float xs[];          // [64][512] = 128 KB
  __shared__ float rms[TT];
  __shared__ float sp[TT];
  int b = blockIdx.x, tid = threadIdx.x;
  int l = tid & 63, w = tid >> 6;        // 8 waves
  #pragma unroll
  for (int p = 0; p < 16; ++p) {
    int f = p * 512 + tid;
    int t = f >> 7, c4 = f & 127;        // row t, float4 col c4
    gload16(x + (size_t)t * (BB * NN) + (size_t)b * NN + c4 * 4,
            (char*)xs + p * 8192 + w * 1024);
  }
  __syncthreads();                       // drains vmcnt(0) before barrier
  // own column into registers (64 independent ds_reads)
  float xcol[TT];
  #pragma unroll
  for (int t = 0; t < TT; ++t) xcol[t] = xs[t * 512 + tid];
  float cs = 0.f;
  #pragma unroll
  for (int t = 0; t < TT; ++t) cs += xcol[t];
  // row sums: wave w owns rows w*8..w*8+7
  #pragma unroll
  for (int j = 0; j < 8; ++j) {
    int t = w * 8 + j;
    float s = 0.f;
    #pragma unroll
    for (int q = 0; q < 8; ++q) s += xs[t * 512 + q * 64 + l];
    #pragma unroll
    for (int off = 32; off; off >>= 1) s += __shfl_xor(s, off);
    if (l == 0) rms[t] = s;
  }
  __syncthreads();
  // spatial LIF scan: wave 0, register chain via shfl broadcast
  if (w == 0) {
    float myrm = rms[l];
    float v = 0.f;
    unsigned long long mask = 0ull;
    #pragma unroll
    for (int t = 0; t < TT; ++t) {
      float m = __shfl(myrm, t) * (1.0f / 512.0f);
      v = v * 0.5f + m;                  // == v - v/2 + m exactly
      if (v >= 1.0f) { mask |= (1ull << t); v = 0.f; }
    }
    sp[l] = (float)((mask >> l) & 1ull);
  }
  __syncthreads();
  float te = (cs * (1.0f / 64.0f) >= 1.0f) ? 1.0f : 0.0f;
  float v = 0.f;
  // chunk-layout spike store: kc=n>>5, l=(b&31)+32*bit4(n), j=n&15
  unsigned char* sb = spkT + (size_t)((b >> 5) * 16 + (tid >> 5)) * 1024
                    + ((b & 31) + 32 * ((tid >> 4) & 1)) * 16 + (tid & 15);
  #pragma unroll
  for (int t = 0; t < TT; ++t) {
    float xv = xcol[t];
    float a = xv + (xv * sp[t]) * (xv * te);  // ==xv exactly when a gate is 0
    v = v * 0.5f + a;
    unsigned char s = (v >= 1.0f) ? 1 : 0;
    sb[(size_t)t * 131072] = s;          // rg advances 8 chunks per t
    if (s) v = 0.f;
  }
}

// ---------------------------------------------------------------------------
// K2: i8 MFMA GEMM, 2x24KB double-buffer (48KB -> 3 blocks/CU via LDS; NO
// min-waves bound -- R6's bound spilled the 128-reg accumulator to scratch).
// All staging is gload16 from chunk-layout buffers: lane-contiguous sources.
// Per iter t: lgkmcnt(0); vmcnt(0); s_barrier; STAGE(t+1) into freed buffer;
// ds_read buf[t&1]; setprio(1); 16 MFMA.
// ---------------------------------------------------------------------------
__global__ __launch_bounds__(256) void gemm_kernel(
    const unsigned char* __restrict__ AT, const signed char* __restrict__ WT,
    float* __restrict__ C, float* __restrict__ pS, float* __restrict__ pQ) {
  __shared__ unsigned char sm[2][24576];
  int tid = threadIdx.x;
  int l = tid & 63, w = tid >> 6;
  int wr = w >> 1, wc = w & 1;
  int bx = blockIdx.x, by = blockIdx.y;
  int row0 = bx * 128, col0 = by * 64;
  int lr = l & 31, lh = l >> 5;

  i32x16 acc[2][4];
  #pragma unroll
  for (int f = 0; f < 2; ++f)
    #pragma unroll
    for (int d = 0; d < 4; ++d)
      #pragma unroll
      for (int j = 0; j < 16; ++j) acc[f][d][j] = 0;

  auto STAGE = [&](unsigned char* lbase, int t) {
    #pragma unroll
    for (int j = 0; j < 2; ++j) {        // A chunks: c = wr_*4 + ff*2 + ss
      int c = j * 4 + w;
      int rg = bx * 4 + (c >> 2) * 2 + ((c >> 1) & 1);
      int kc = t * 2 + (c & 1);
      gload16(AT + (size_t)(rg * 16 + kc) * 1024 + l * 16, lbase + c * 1024);
    }
    #pragma unroll
    for (int j = 0; j < 4; ++j) {        // B chunks: c2 = cg_loc*8 + dd*2 + ss
      int c2 = j * 4 + w;
      int cg = by * 2 + (c2 >> 3), dd = (c2 >> 1) & 3, ss = c2 & 1;
      gload16(WT + (size_t)((cg * 4 + dd) * 16 + t * 2 + ss) * 1024 + l * 16,
              lbase + 8192 + c2 * 1024);
    }
  };

  STAGE(sm[0], 0);
  #pragma unroll
  for (int t = 0; t < 8; ++t) {
    asm volatile("s_waitcnt lgkmcnt(0)" ::: "memory");  // my prev-buf reads done
    asm volatile("s_waitcnt vmcnt(0)" ::: "memory");    // my stage of buf[t&1] landed
    asm volatile("s_barrier" ::: "memory");             // all waves agree
    if (t < 7) STAGE(sm[(t + 1) & 1], t + 1);           // refill freed buffer
    const unsigned char* bp = sm[t & 1];
    i32x4 a[2][2], bfr[4][2];
    #pragma unroll
    for (int f = 0; f < 2; ++f)
      #pragma unroll
      for (int s = 0; s < 2; ++s)
        a[f][s] = *(const i32x4*)(bp + ((wr * 2 + f) * 2 + s) * 1024 + l * 16);
    #pragma unroll
    for (int d = 0; d < 4; ++d)
      #pragma unroll
      for (int s = 0; s < 2; ++s)
        bfr[d][s] = *(const i32x4*)(bp + 8192 + ((wc * 4 + d) * 2 + s) * 1024 + l * 16);
    __builtin_amdgcn_s_setprio(1);
    #pragma unroll
    for (int s = 0; s < 2; ++s)
      #pragma unroll
      for (int f = 0; f < 2; ++f)
        #pragma unroll
        for (int d = 0; d < 4; ++d)
          acc[f][d] = __builtin_amdgcn_mfma_i32_32x32x32_i8(a[f][s], bfr[d][s], acc[f][d], 0, 0, 0);
    __builtin_amdgcn_s_setprio(0);
  }

  // epilogue: exact digit combine, C write, BN partials.
  // lanes lh=0/1 share a column, different rows -> combine across lane^32.
  int col = col0 + wc * 32 + lr;
  float sy = 0.f, sq = 0.f;
  #pragma unroll
  for (int f = 0; f < 2; ++f) {
    #pragma unroll
    for (int j = 0; j < 16; ++j) {
      int t2 = acc[f][2][j] + (acc[f][3][j] << 8);
      int t1 = acc[f][1][j] + (t2 << 8);
      long long tt = ((long long)t1 << 8) + (long long)acc[f][0][j];
      float y = (float)tt * 0x1p-30f;
      int row = row0 + wr * 64 + f * 32 + (j & 3) + 8 * (j >> 2) + 4 * lh;
      C[(size_t)row * NN + col] = y;
      sy += y; sq += y * y;
    }
  }
  sy += __shfl_xor(sy, 32);
  sq += __shfl_xor(sq, 32);
  if (lh == 0) {
    pS[(size_t)col * 256 + bx * 2 + wr] = sy;
    pQ[(size_t)col * 256 + bx * 2 + wr] = sq;
  }
}

// ---------------------------------------------------------------------------
// K3: reduce 256 BN partials per channel -> mu, inv-std
// ---------------------------------------------------------------------------
__global__ __launch_bounds__(512) void bnstatsB_kernel(
    const float* __restrict__ pS, const float* __restrict__ pQ,
    float* __restrict__ mu, float* __restrict__ inv) {
  int tid = threadIdx.x;
  int ch = blockIdx.x * 64 + (tid >> 3), p = tid & 7;
  const float* ps = pS + (size_t)ch * 256 + p * 32;
  const float* pq = pQ + (size_t)ch * 256 + p * 32;
  float s = 0.f, q = 0.f;
  #pragma unroll
  for (int i = 0; i < 32; ++i) { s += ps[i]; q += pq[i]; }
  #pragma unroll
  for (int off = 1; off < 8; off <<= 1) { s += __shfl_xor(s, off); q += __shfl_xor(q, off); }
  if (p == 0) {
    float mean = s * (1.0f / 16384.0f);
    float var  = q * (1.0f / 16384.0f) - mean * mean;
    mu[ch] = mean;
    inv[ch] = 1.0f / sqrtf(var + 1e-5f);
  }
}

// ---------------------------------------------------------------------------
// K4: BN normalize + final LIF scan, in-place on d_out, 16-deep load prefetch
// ---------------------------------------------------------------------------
__global__ __launch_bounds__(256) void final_kernel(
    float* __restrict__ y, const float* __restrict__ mu, const float* __restrict__ inv,
    const float* __restrict__ gamma, const float* __restrict__ beta) {
  int g = blockIdx.x * 256 + threadIdx.x;   // (b, m)
  int b = g >> 9, m = g & 511;
  float MU = mu[m], IV = inv[m], G = gamma[m], BE = beta[m];
  float* p = y + (size_t)b * NN + m;
  const size_t st = (size_t)BB * NN;
  float buf[16], nxt[16];
  #pragma unroll
  for (int j = 0; j < 16; ++j) buf[j] = p[(size_t)j * st];
  float v = 0.f;
  #pragma unroll
  for (int t0 = 0; t0 < 64; t0 += 16) {
    if (t0 + 16 < 64) {
      #pragma unroll
      for (int j = 0; j < 16; ++j) nxt[j] = p[(size_t)(t0 + 16 + j) * st];
    }
    #pragma unroll
    for (int j = 0; j < 16; ++j) {
      float xb = (buf[j] - MU) * IV * G + BE;
      v = v * 0.5f + xb;
      float s = (v >= 1.0f) ? 1.0f : 0.0f;
      p[(size_t)(t0 + j) * st] = s;
      if (s != 0.f) v = 0.f;
    }
    #pragma unroll
    for (int j = 0; j < 16; ++j) buf[j] = nxt[j];
  }
}

// ---------------------------------------------------------------------------
extern "C" void kernel_launch(void* const* d_in, const int* in_sizes, int n_in,
                              void* d_out, int out_size, void* d_ws, size_t ws_size,
                              hipStream_t stream) {
  const float* x     = (const float*)d_in[0];   // [T,B,N]
  const float* W     = (const float*)d_in[1];   // [N,N]
  const float* gamma = (const float*)d_in[2];   // [N]
  const float* beta  = (const float*)d_in[3];   // [N]
  float* out = (float*)d_out;                   // [T,B,N] fp32

  // workspace layout (~10.5 MB)
  char* ws = (char*)d_ws;
  signed char* wdT      = (signed char*)ws;                 // 1,048,576
  unsigned char* spkT   = (unsigned char*)(ws + 1048576);   // 8,388,608
  float* pS    = (float*)(ws + 9437184);                    //   524,288
  float* pQ    = (float*)(ws + 9961472);                    //   524,288
  float* bn_mu = (float*)(ws + 10485760);                   //     2,048
  float* bn_inv= (float*)(ws + 10487808);                   //     2,048

  wprep_kernel<<<dim3(1024), dim3(256), 0, stream>>>(W, wdT);
  frontend_kernel<<<dim3(BB), dim3(512), 131072, stream>>>(x, spkT);
  gemm_kernel<<<dim3(128, 8), dim3(256), 0, stream>>>(spkT, wdT, out, pS, pQ);
  bnstatsB_kernel<<<dim3(8), dim3(512), 0, stream>>>(pS, pQ, bn_mu, bn_inv);
  final_kernel<<<dim3(512), dim3(256), 0, stream>>>(out, bn_mu, bn_inv, gamma, beta);
}